// Round 5
// baseline (695.913 us; speedup 1.0000x reference)
//
#include <hip/hip_runtime.h>

// MetaUpscale: out[n,o,oy,ox] = sum_{ch<576} patch[n][oy/2][ox/2][ch] * lw[oy][ox][ch][o]
// patch[n][hy][wx][c*9+kh*3+kw] = x[n][c][hy+kh-1][wx+kw-1] (zero pad). FP32.
//
// R5 "strip" design: block = 8 consecutive input pixels at one row (grid 2048).
// x window [2][64][3][10] staged to LDS once (one barrier), then each wave
// streams its sub-pixel's lw chunks as float4 (perfect coalescing, 7
// wave-instrs/pixel) with a 2-deep pixel prefetch so vmcnt never drains.
// Since 256 = 4 = 1 (mod 3): component j of float4 k has o=(k+j+lane)%3 ->
// accumulate into acc[(k+j)%3] (static) and rotate by lane%3 at the end
// (numerically validated in R3/R4). LDS patch indices decode once per wave.
//
// NOTE: kernel launched TWICE this round (idempotent) to measure the kernel
// slice: R5 - R4 = 2*K_new - K_old.

namespace {

constexpr int C_    = 64;
constexpr int H_    = 128;
constexpr int W_    = 128;
constexpr int CH9   = 576;
constexpr int OH_   = 256;
constexpr int OW_   = 256;
constexpr int STRIP = 8;                 // input pixels per block
constexpr int XCOLS = STRIP + 2;         // 10 staged columns (halo)
constexpr int NOFF  = C_ * 3 * XCOLS;    // 1920: n-stride in xs
constexpr int F4PP  = CH9 * 3 / 4;       // 432 float4 per output pixel

__global__ __launch_bounds__(256)
void metaupscale_kernel(const float* __restrict__ x,
                        const float* __restrict__ lw,
                        float* __restrict__ out) {
    __shared__ float xs[2 * NOFF];       // 15360 B

    const int blk = blockIdx.x;          // 2048 blocks
    const int hy  = blk >> 4;
    const int wx0 = (blk & 15) * STRIP;
    const int tid = threadIdx.x;

    // ---- Stage x window: rows hy-1..hy+1, cols wx0-1..wx0+8, both n ----
    for (int f = tid; f < 2 * NOFF; f += 256) {
        const int wcol = f % XCOLS;
        const int g    = f / XCOLS;
        const int kh   = g % 3;
        const int h2   = g / 3;
        const int c    = h2 & 63;
        const int n    = h2 >> 6;
        const int hh   = hy + kh - 1;
        const int wwc  = wx0 + wcol - 1;
        float v = 0.0f;
        if ((unsigned)hh < (unsigned)H_ && (unsigned)wwc < (unsigned)W_)
            v = x[((n * C_ + c) * H_ + hh) * W_ + wwc];
        xs[f] = v;
    }

    const int wave = tid >> 6, lane = tid & 63;
    const int sy = wave >> 1, sx = wave & 1;
    const int oy = 2 * hy + sy;
    const int r  = lane % 3;

    // ---- Per-k lane constants (outside pixel loop) ----
    int iA[7], iB[7], r0[7];
    #pragma unroll
    for (int k = 0; k < 7; ++k) {
        const int e0  = 256 * k + 4 * lane;
        int ch0 = e0 / 3;  if (ch0 > CH9 - 1) ch0 = CH9 - 1;   // clamp for tail lanes
        int ch1 = ch0 + 1; if (ch1 > CH9 - 1) ch1 = CH9 - 1;
        r0[k] = (k + lane) % 3;
        const int cA = ch0 / 9, jA = ch0 - cA * 9;
        const int cB = ch1 / 9, jB = ch1 - cB * 9;
        iA[k] = (cA * 3 + jA / 3) * XCOLS + (jA % 3);
        iB[k] = (cB * 3 + jB / 3) * XCOLS + (jB % 3);
    }

    __syncthreads();

    const float4* __restrict__ lw4 = (const float4*)lw;

    float4 wb[2][7];
    {   // prefetch pixel t=0
        const size_t cb = (size_t)(oy * OW_ + (2 * wx0 + sx)) * F4PP;
        #pragma unroll
        for (int k = 0; k < 6; ++k) wb[0][k] = lw4[cb + 64 * k + lane];
        wb[0][6] = (lane < 48) ? lw4[cb + 384 + lane] : make_float4(0.f, 0.f, 0.f, 0.f);
    }

    #pragma unroll
    for (int t = 0; t < STRIP; ++t) {
        const int cur = t & 1;
        if (t + 1 < STRIP) {   // prefetch pixel t+1 before consuming t
            const size_t cb = (size_t)(oy * OW_ + (2 * (wx0 + t + 1) + sx)) * F4PP;
            #pragma unroll
            for (int k = 0; k < 6; ++k) wb[cur ^ 1][k] = lw4[cb + 64 * k + lane];
            wb[cur ^ 1][6] = (lane < 48) ? lw4[cb + 384 + lane]
                                         : make_float4(0.f, 0.f, 0.f, 0.f);
        }

        float acc[2][3] = {};
        #pragma unroll
        for (int k = 0; k < 7; ++k) {
            const float4 w4 = wb[cur][k];
            const float A0 = xs[iA[k] + t];
            const float B0 = xs[iB[k] + t];
            const float A1 = xs[NOFF + iA[k] + t];
            const float B1 = xs[NOFF + iB[k] + t];
            const bool  s1 = (r0[k] == 2), s2 = (r0[k] >= 1);
            const float p1_0 = s1 ? B0 : A0, p2_0 = s2 ? B0 : A0;
            const float p1_1 = s1 ? B1 : A1, p2_1 = s2 ? B1 : A1;
            const int m0 = k % 3, m1 = (k + 1) % 3, m2 = (k + 2) % 3;
            acc[0][m0] += A0   * w4.x;   acc[1][m0] += A1   * w4.x;  // j=0: ch0
            acc[0][m1] += p1_0 * w4.y;   acc[1][m1] += p1_1 * w4.y;  // j=1
            acc[0][m2] += p2_0 * w4.z;   acc[1][m2] += p2_1 * w4.z;  // j=2
            acc[0][m0] += B0   * w4.w;   acc[1][m0] += B1   * w4.w;  // j=3: ch0+1, m=(k+3)%3
        }

        // rotate m -> true o per lane (o = (m + r) % 3)
        float racc[2][3];
        #pragma unroll
        for (int n = 0; n < 2; ++n) {
            #pragma unroll
            for (int o = 0; o < 3; ++o) {
                const int m = (o - r + 3) % 3;
                racc[n][o] = (m == 0) ? acc[n][0] : (m == 1) ? acc[n][1] : acc[n][2];
            }
        }

        #pragma unroll
        for (int off = 32; off > 0; off >>= 1) {
            #pragma unroll
            for (int n = 0; n < 2; ++n) {
                #pragma unroll
                for (int o = 0; o < 3; ++o) {
                    racc[n][o] += __shfl_down(racc[n][o], off, 64);
                }
            }
        }

        if (lane == 0) {
            const int ox = 2 * (wx0 + t) + sx;
            #pragma unroll
            for (int n = 0; n < 2; ++n) {
                #pragma unroll
                for (int o = 0; o < 3; ++o) {
                    out[(((size_t)n * 3 + o) * OH_ + oy) * OW_ + ox] = racc[n][o];
                }
            }
        }
    }
}

}  // namespace

extern "C" void kernel_launch(void* const* d_in, const int* in_sizes, int n_in,
                              void* d_out, int out_size, void* d_ws, size_t ws_size,
                              hipStream_t stream) {
    const float* x  = (const float*)d_in[0];
    const float* lw = (const float*)d_in[1];
    float* out = (float*)d_out;

    const int grid = H_ * 16;   // 2048 blocks: 128 rows x 16 strips
    // Launched TWICE (idempotent) this round to measure the kernel slice:
    // dur_us = overhead + 2*K. Same work every call (graph-capture safe).
    metaupscale_kernel<<<grid, 256, 0, stream>>>(x, lw, out);
    metaupscale_kernel<<<grid, 256, 0, stream>>>(x, lw, out);
}